// Round 1
// baseline (3705.957 us; speedup 1.0000x reference)
//
#include <hip/hip_runtime.h>

// ---------------------------------------------------------------------------
// PMLP forward: 3 x (GEMM -> symmetric-norm propagate -> bias[+relu])
// N=50000 nodes, E=800000 edges, dims 128->128->128->64, fp32.
// ---------------------------------------------------------------------------

// deg[col] += 1 per edge (self-loop +1 folded into k_dinv)
__global__ __launch_bounds__(256) void k_deg(const int* __restrict__ ei,
                                             float* __restrict__ deg, int E) {
    int e = blockIdx.x * 256 + threadIdx.x;
    if (e < E) atomicAdd(&deg[ei[E + e]], 1.0f);
}

__global__ __launch_bounds__(256) void k_dinv(const float* __restrict__ deg,
                                              float* __restrict__ dinv, int n) {
    int i = blockIdx.x * 256 + threadIdx.x;
    if (i < n) dinv[i] = rsqrtf(deg[i] + 1.0f);  // +1 = self loop
}

// C[m][n] = sum_k X[m][k] * W[n][k]; K fixed = 128, N in {64,128}.
// 64x64 block tile, 256 threads, 4x4 microtile, K-major LDS staging.
__global__ __launch_bounds__(256) void k_gemm(const float* __restrict__ X,
                                              const float* __restrict__ W,
                                              float* __restrict__ C,
                                              int M, int N) {
    __shared__ float Xs[128][64];  // [k][m]  32 KB
    __shared__ float Ws[128][64];  // [k][n]  32 KB
    const int tid = threadIdx.x;
    const int m0 = blockIdx.x * 64;
    const int n0 = blockIdx.y * 64;

    // Stage: 64 rows x 128 K for both X and W, coalesced float4 global reads.
    // (Transposed LDS writes have bank conflicts; once per block, amortized.)
#pragma unroll
    for (int it = 0; it < 8; ++it) {
        int i = tid + it * 256;
        int r = i >> 5;   // row 0..63
        int j = i & 31;   // float4 index along K
        int gm = m0 + r;
        float4 v = make_float4(0.f, 0.f, 0.f, 0.f);
        if (gm < M) v = reinterpret_cast<const float4*>(X + (size_t)gm * 128)[j];
        Xs[4 * j + 0][r] = v.x; Xs[4 * j + 1][r] = v.y;
        Xs[4 * j + 2][r] = v.z; Xs[4 * j + 3][r] = v.w;
        float4 w = reinterpret_cast<const float4*>(W + (size_t)(n0 + r) * 128)[j];
        Ws[4 * j + 0][r] = w.x; Ws[4 * j + 1][r] = w.y;
        Ws[4 * j + 2][r] = w.z; Ws[4 * j + 3][r] = w.w;
    }
    __syncthreads();

    const int tx = tid & 15;   // n quad
    const int ty = tid >> 4;   // m quad
    float acc[4][4] = {};
#pragma unroll 8
    for (int k = 0; k < 128; ++k) {
        float4 a = *reinterpret_cast<const float4*>(&Xs[k][4 * ty]);
        float4 b = *reinterpret_cast<const float4*>(&Ws[k][4 * tx]);
        acc[0][0] += a.x * b.x; acc[0][1] += a.x * b.y; acc[0][2] += a.x * b.z; acc[0][3] += a.x * b.w;
        acc[1][0] += a.y * b.x; acc[1][1] += a.y * b.y; acc[1][2] += a.y * b.z; acc[1][3] += a.y * b.w;
        acc[2][0] += a.z * b.x; acc[2][1] += a.z * b.y; acc[2][2] += a.z * b.z; acc[2][3] += a.z * b.w;
        acc[3][0] += a.w * b.x; acc[3][1] += a.w * b.y; acc[3][2] += a.w * b.z; acc[3][3] += a.w * b.w;
    }
#pragma unroll
    for (int r = 0; r < 4; ++r) {
        int gm = m0 + 4 * ty + r;
        if (gm < M) {
            float4 o = make_float4(acc[r][0], acc[r][1], acc[r][2], acc[r][3]);
            *reinterpret_cast<float4*>(C + (size_t)gm * N + n0 + 4 * tx) = o;
        }
    }
}

// A[i][:] = dinv[i]^2 * P[i][:]   (self-loop term; also serves as zero-init)
template <int LOGC>
__global__ __launch_bounds__(256) void k_selfinit(const float* __restrict__ P,
                                                  const float* __restrict__ dinv,
                                                  float* __restrict__ A, int n) {
    int t = blockIdx.x * 256 + threadIdx.x;
    int i = t >> LOGC;
    int c = t & ((1 << LOGC) - 1);
    if (i >= n) return;
    const int D = 4 << LOGC;
    float s = dinv[i]; s *= s;
    float4 v = reinterpret_cast<const float4*>(P + (size_t)i * D)[c];
    float4 o = make_float4(s * v.x, s * v.y, s * v.z, s * v.w);
    reinterpret_cast<float4*>(A + (size_t)i * D)[c] = o;
}

// A[col][:] += dinv[row]*dinv[col] * P[row][:]  per edge, fp32 atomics
template <int LOGC>
__global__ __launch_bounds__(256) void k_scatter(const float* __restrict__ P,
                                                 const int* __restrict__ ei,
                                                 const float* __restrict__ dinv,
                                                 float* __restrict__ A, int E) {
    int t = blockIdx.x * 256 + threadIdx.x;
    int e = t >> LOGC;
    int c = t & ((1 << LOGC) - 1);
    if (e >= E) return;
    const int D = 4 << LOGC;
    int r  = ei[e];
    int co = ei[E + e];
    float nrm = dinv[r] * dinv[co];
    float4 v = reinterpret_cast<const float4*>(P + (size_t)r * D)[c];
    float* dst = A + (size_t)co * D + 4 * c;
    atomicAdd(dst + 0, nrm * v.x);
    atomicAdd(dst + 1, nrm * v.y);
    atomicAdd(dst + 2, nrm * v.z);
    atomicAdd(dst + 3, nrm * v.w);
}

// H[i][:] = (A[i][:] + b)  [relu]
template <int LOGC, bool RELU>
__global__ __launch_bounds__(256) void k_bias(const float* __restrict__ A,
                                              const float* __restrict__ bias,
                                              float* __restrict__ H, int n) {
    int t = blockIdx.x * 256 + threadIdx.x;
    int i = t >> LOGC;
    int c = t & ((1 << LOGC) - 1);
    if (i >= n) return;
    const int D = 4 << LOGC;
    float4 v = reinterpret_cast<const float4*>(A + (size_t)i * D)[c];
    float4 b = reinterpret_cast<const float4*>(bias)[c];
    float4 o = make_float4(v.x + b.x, v.y + b.y, v.z + b.z, v.w + b.w);
    if (RELU) {
        o.x = fmaxf(o.x, 0.f); o.y = fmaxf(o.y, 0.f);
        o.z = fmaxf(o.z, 0.f); o.w = fmaxf(o.w, 0.f);
    }
    reinterpret_cast<float4*>(H + (size_t)i * D)[c] = o;
}

extern "C" void kernel_launch(void* const* d_in, const int* in_sizes, int n_in,
                              void* d_out, int out_size, void* d_ws, size_t ws_size,
                              hipStream_t stream) {
    const float* x  = (const float*)d_in[0];
    const int*   ei = (const int*)d_in[1];   // [2][E] int32 (jax x64 off)
    const float* W0 = (const float*)d_in[2];
    const float* b0 = (const float*)d_in[3];
    const float* W1 = (const float*)d_in[4];
    const float* b1 = (const float*)d_in[5];
    const float* W2 = (const float*)d_in[6];
    const float* b2 = (const float*)d_in[7];
    float* out = (float*)d_out;

    const int n = in_sizes[0] / 128;   // 50000
    const int E = in_sizes[1] / 2;     // 800000

    // workspace layout (fp32): deg | dinv | P | A | H   = ~77.3 MB
    float* deg  = (float*)d_ws;
    float* dinv = deg + 51200;
    float* bufP = dinv + 51200;
    float* bufA = bufP + (size_t)n * 128;
    float* bufH = bufA + (size_t)n * 128;

    hipMemsetAsync(deg, 0, (size_t)n * sizeof(float), stream);
    k_deg<<<(E + 255) / 256, 256, 0, stream>>>(ei, deg, E);
    k_dinv<<<(n + 255) / 256, 256, 0, stream>>>(deg, dinv, n);

    dim3 g128((n + 63) / 64, 2);
    dim3 g64((n + 63) / 64, 1);
    int tN128 = n * 32, tE128 = E * 32;   // thread counts (D/4 chunks)
    int tN64  = n * 16, tE64  = E * 16;

    // ---- Layer 0: h = relu(propagate(x@W0^T) + b0)
    k_gemm<<<g128, 256, 0, stream>>>(x, W0, bufP, n, 128);
    k_selfinit<5><<<(tN128 + 255) / 256, 256, 0, stream>>>(bufP, dinv, bufA, n);
    k_scatter<5><<<(tE128 + 255) / 256, 256, 0, stream>>>(bufP, ei, dinv, bufA, E);
    k_bias<5, true><<<(tN128 + 255) / 256, 256, 0, stream>>>(bufA, b0, bufH, n);

    // ---- Layer 1
    k_gemm<<<g128, 256, 0, stream>>>(bufH, W1, bufP, n, 128);
    k_selfinit<5><<<(tN128 + 255) / 256, 256, 0, stream>>>(bufP, dinv, bufA, n);
    k_scatter<5><<<(tE128 + 255) / 256, 256, 0, stream>>>(bufP, ei, dinv, bufA, E);
    k_bias<5, true><<<(tN128 + 255) / 256, 256, 0, stream>>>(bufA, b1, bufH, n);

    // ---- Layer 2 (out dim 64, no relu)
    k_gemm<<<g64, 256, 0, stream>>>(bufH, W2, bufP, n, 64);
    k_selfinit<4><<<(tN64 + 255) / 256, 256, 0, stream>>>(bufP, dinv, bufA, n);
    k_scatter<4><<<(tE64 + 255) / 256, 256, 0, stream>>>(bufP, ei, dinv, bufA, E);
    k_bias<4, false><<<(tN64 + 255) / 256, 256, 0, stream>>>(bufA, b2, out, n);
}

// Round 2
// 544.974 us; speedup vs baseline: 6.8002x; 6.8002x over previous
//
#include <hip/hip_runtime.h>

// ---------------------------------------------------------------------------
// PMLP forward: 3 x (GEMM -> symmetric-norm propagate -> bias[+relu])
// N=50000 nodes, E=800000 edges, dims 128->128->128->64, fp32.
// R2: scatter-atomics -> CSR-bucketed gather (zero fp atomics in hot path).
// ---------------------------------------------------------------------------

__global__ __launch_bounds__(256) void k_deg(const int* __restrict__ ei,
                                             int* __restrict__ counts, int E) {
    int e = blockIdx.x * 256 + threadIdx.x;
    if (e < E) atomicAdd(&counts[ei[E + e]], 1);
}

__global__ __launch_bounds__(256) void k_dinv(const int* __restrict__ counts,
                                              float* __restrict__ dinv, int n) {
    int i = blockIdx.x * 256 + threadIdx.x;
    if (i < n) dinv[i] = rsqrtf((float)counts[i] + 1.0f);  // +1 = self loop
}

// Exclusive prefix sum of counts[0..n) -> offs[0..n]. Single block, 1024 thr.
__global__ __launch_bounds__(1024) void k_scan(const int* __restrict__ counts,
                                               int* __restrict__ offs, int n) {
    __shared__ int wsum[17];
    const int lane = threadIdx.x & 63;
    const int wid = threadIdx.x >> 6;  // 16 waves
    int carry = 0;
    for (int base = 0; base < n; base += 1024) {
        int i = base + threadIdx.x;
        int v = (i < n) ? counts[i] : 0;
        int s = v;  // wave-inclusive scan via shuffles
#pragma unroll
        for (int off = 1; off < 64; off <<= 1) {
            int t = __shfl_up(s, off);
            if (lane >= off) s += t;
        }
        if (lane == 63) wsum[wid] = s;
        __syncthreads();
        if (threadIdx.x == 0) {
            int a = 0;
            for (int w = 0; w < 16; ++w) { int t = wsum[w]; wsum[w] = a; a += t; }
            wsum[16] = a;
        }
        __syncthreads();
        if (i < n) offs[i] = carry + wsum[wid] + s - v;  // exclusive
        carry += wsum[16];
        __syncthreads();  // protect wsum before next chunk overwrites
    }
    if (threadIdx.x == 0) offs[n] = carry;
}

// Bucket edges by destination: edata[offs[col]+k] = (row, dinv[row]*dinv[col])
__global__ __launch_bounds__(256) void k_fill(const int* __restrict__ ei,
                                              const int* __restrict__ offs,
                                              int* __restrict__ cursor,
                                              const float* __restrict__ dinv,
                                              int2* __restrict__ edata, int E) {
    int e = blockIdx.x * 256 + threadIdx.x;
    if (e >= E) return;
    int r = ei[e];
    int c = ei[E + e];
    int pos = atomicAdd(&cursor[c], 1);
    int2 d;
    d.x = r;
    d.y = __float_as_int(dinv[r] * dinv[c]);
    edata[offs[c] + pos] = d;
}

// C[m][n] = sum_k X[m][k] * W[n][k]; K fixed = 128, N in {64,128}.
// 64x64 block tile, 256 threads, 4x4 microtile, K-major LDS staging.
__global__ __launch_bounds__(256) void k_gemm(const float* __restrict__ X,
                                              const float* __restrict__ W,
                                              float* __restrict__ C,
                                              int M, int N) {
    __shared__ float Xs[128][64];  // [k][m]  32 KB
    __shared__ float Ws[128][64];  // [k][n]  32 KB
    const int tid = threadIdx.x;
    const int m0 = blockIdx.x * 64;
    const int n0 = blockIdx.y * 64;

#pragma unroll
    for (int it = 0; it < 8; ++it) {
        int i = tid + it * 256;
        int r = i >> 5;   // row 0..63
        int j = i & 31;   // float4 index along K
        int gm = m0 + r;
        float4 v = make_float4(0.f, 0.f, 0.f, 0.f);
        if (gm < M) v = reinterpret_cast<const float4*>(X + (size_t)gm * 128)[j];
        Xs[4 * j + 0][r] = v.x; Xs[4 * j + 1][r] = v.y;
        Xs[4 * j + 2][r] = v.z; Xs[4 * j + 3][r] = v.w;
        float4 w = reinterpret_cast<const float4*>(W + (size_t)(n0 + r) * 128)[j];
        Ws[4 * j + 0][r] = w.x; Ws[4 * j + 1][r] = w.y;
        Ws[4 * j + 2][r] = w.z; Ws[4 * j + 3][r] = w.w;
    }
    __syncthreads();

    const int tx = tid & 15;   // n quad
    const int ty = tid >> 4;   // m quad
    float acc[4][4] = {};
#pragma unroll 8
    for (int k = 0; k < 128; ++k) {
        float4 a = *reinterpret_cast<const float4*>(&Xs[k][4 * ty]);
        float4 b = *reinterpret_cast<const float4*>(&Ws[k][4 * tx]);
        acc[0][0] += a.x * b.x; acc[0][1] += a.x * b.y; acc[0][2] += a.x * b.z; acc[0][3] += a.x * b.w;
        acc[1][0] += a.y * b.x; acc[1][1] += a.y * b.y; acc[1][2] += a.y * b.z; acc[1][3] += a.y * b.w;
        acc[2][0] += a.z * b.x; acc[2][1] += a.z * b.y; acc[2][2] += a.z * b.z; acc[2][3] += a.z * b.w;
        acc[3][0] += a.w * b.x; acc[3][1] += a.w * b.y; acc[3][2] += a.w * b.z; acc[3][3] += a.w * b.w;
    }
#pragma unroll
    for (int r = 0; r < 4; ++r) {
        int gm = m0 + 4 * ty + r;
        if (gm < M) {
            float4 o = make_float4(acc[r][0], acc[r][1], acc[r][2], acc[r][3]);
            *reinterpret_cast<float4*>(C + (size_t)gm * N + n0 + 4 * tx) = o;
        }
    }
}

// H[dst][:] = relu?( dinv[dst]^2 * P[dst][:]
//                    + sum_{in-edges} norm * P[row][:] + bias )
// DQ = D/4 lanes per node, each lane owns one float4 column chunk.
template <int DQ, bool RELU>
__global__ __launch_bounds__(256) void k_gather(const float* __restrict__ P,
                                                const int* __restrict__ offs,
                                                const int2* __restrict__ edata,
                                                const float* __restrict__ dinv,
                                                const float* __restrict__ bias,
                                                float* __restrict__ H, int n) {
    int t = blockIdx.x * 256 + threadIdx.x;
    int node = t / DQ;
    int c = t % DQ;
    if (node >= n) return;
    const int D = DQ * 4;

    float s = dinv[node];
    s *= s;
    float4 pv = reinterpret_cast<const float4*>(P + (size_t)node * D)[c];
    float4 acc = make_float4(s * pv.x, s * pv.y, s * pv.z, s * pv.w);

    int j = offs[node];
    const int end = offs[node + 1];
    for (; j < end; ++j) {
        int2 ed = edata[j];
        float nrm = __int_as_float(ed.y);
        float4 v = reinterpret_cast<const float4*>(P + (size_t)ed.x * D)[c];
        acc.x += nrm * v.x; acc.y += nrm * v.y;
        acc.z += nrm * v.z; acc.w += nrm * v.w;
    }
    float4 b = reinterpret_cast<const float4*>(bias)[c];
    acc.x += b.x; acc.y += b.y; acc.z += b.z; acc.w += b.w;
    if (RELU) {
        acc.x = fmaxf(acc.x, 0.f); acc.y = fmaxf(acc.y, 0.f);
        acc.z = fmaxf(acc.z, 0.f); acc.w = fmaxf(acc.w, 0.f);
    }
    reinterpret_cast<float4*>(H + (size_t)node * D)[c] = acc;
}

extern "C" void kernel_launch(void* const* d_in, const int* in_sizes, int n_in,
                              void* d_out, int out_size, void* d_ws, size_t ws_size,
                              hipStream_t stream) {
    const float* x  = (const float*)d_in[0];
    const int*   ei = (const int*)d_in[1];   // [2][E] int32
    const float* W0 = (const float*)d_in[2];
    const float* b0 = (const float*)d_in[3];
    const float* W1 = (const float*)d_in[4];
    const float* b1 = (const float*)d_in[5];
    const float* W2 = (const float*)d_in[6];
    const float* b2 = (const float*)d_in[7];
    float* out = (float*)d_out;

    const int n = in_sizes[0] / 128;   // 50000
    const int E = in_sizes[1] / 2;     // 800000

    // workspace: counts | offs | cursor | dinv | edata | P | H   (~59 MB)
    int*   counts = (int*)d_ws;
    int*   offs   = counts + 51200;
    int*   cursor = offs + 51200;
    float* dinv   = (float*)(cursor + 51200);
    int2*  edata  = (int2*)(dinv + 51200);
    float* bufP   = (float*)(edata + E);
    float* bufH   = bufP + (size_t)n * 128;

    // ---- CSR build (once, reused by all 3 layers)
    hipMemsetAsync(counts, 0, (size_t)n * sizeof(int), stream);
    hipMemsetAsync(cursor, 0, (size_t)n * sizeof(int), stream);
    k_deg<<<(E + 255) / 256, 256, 0, stream>>>(ei, counts, E);
    k_dinv<<<(n + 255) / 256, 256, 0, stream>>>(counts, dinv, n);
    k_scan<<<1, 1024, 0, stream>>>(counts, offs, n);
    k_fill<<<(E + 255) / 256, 256, 0, stream>>>(ei, offs, cursor, dinv, edata, E);

    dim3 g128((n + 63) / 64, 2);
    dim3 g64((n + 63) / 64, 1);
    const int gThr128 = n * 32;  // DQ=32 lanes per node
    const int gThr64  = n * 16;  // DQ=16

    // ---- Layer 0: h = relu(propagate(x@W0^T) + b0)
    k_gemm<<<g128, 256, 0, stream>>>(x, W0, bufP, n, 128);
    k_gather<32, true><<<(gThr128 + 255) / 256, 256, 0, stream>>>(
        bufP, offs, edata, dinv, b0, bufH, n);

    // ---- Layer 1
    k_gemm<<<g128, 256, 0, stream>>>(bufH, W1, bufP, n, 128);
    k_gather<32, true><<<(gThr128 + 255) / 256, 256, 0, stream>>>(
        bufP, offs, edata, dinv, b1, bufH, n);

    // ---- Layer 2 (out dim 64, no relu)
    k_gemm<<<g64, 256, 0, stream>>>(bufH, W2, bufP, n, 64);
    k_gather<16, false><<<(gThr64 + 255) / 256, 256, 0, stream>>>(
        bufP, offs, edata, dinv, b2, out, n);
}

// Round 3
// 444.557 us; speedup vs baseline: 8.3363x; 1.2259x over previous
//
#include <hip/hip_runtime.h>

// ---------------------------------------------------------------------------
// PMLP forward: 3 x (GEMM -> symmetric-norm propagate -> bias[+relu])
// N=50000 nodes, E=800000 edges, dims 128->128->128->64, fp32.
// R2: scatter-atomics -> CSR-bucketed gather.
// R3: GEMM LDS staging XOR-swizzle (kills 32-way write conflicts) +
//     K split in two 64-halves (LDS 64KB->32KB, 2->5 blocks/CU).
// ---------------------------------------------------------------------------

__global__ __launch_bounds__(256) void k_deg(const int* __restrict__ ei,
                                             int* __restrict__ counts, int E) {
    int e = blockIdx.x * 256 + threadIdx.x;
    if (e < E) atomicAdd(&counts[ei[E + e]], 1);
}

__global__ __launch_bounds__(256) void k_dinv(const int* __restrict__ counts,
                                              float* __restrict__ dinv, int n) {
    int i = blockIdx.x * 256 + threadIdx.x;
    if (i < n) dinv[i] = rsqrtf((float)counts[i] + 1.0f);  // +1 = self loop
}

// Exclusive prefix sum of counts[0..n) -> offs[0..n]. Single block, 1024 thr.
__global__ __launch_bounds__(1024) void k_scan(const int* __restrict__ counts,
                                               int* __restrict__ offs, int n) {
    __shared__ int wsum[17];
    const int lane = threadIdx.x & 63;
    const int wid = threadIdx.x >> 6;  // 16 waves
    int carry = 0;
    for (int base = 0; base < n; base += 1024) {
        int i = base + threadIdx.x;
        int v = (i < n) ? counts[i] : 0;
        int s = v;
#pragma unroll
        for (int off = 1; off < 64; off <<= 1) {
            int t = __shfl_up(s, off);
            if (lane >= off) s += t;
        }
        if (lane == 63) wsum[wid] = s;
        __syncthreads();
        if (threadIdx.x == 0) {
            int a = 0;
            for (int w = 0; w < 16; ++w) { int t = wsum[w]; wsum[w] = a; a += t; }
            wsum[16] = a;
        }
        __syncthreads();
        if (i < n) offs[i] = carry + wsum[wid] + s - v;  // exclusive
        carry += wsum[16];
        __syncthreads();
    }
    if (threadIdx.x == 0) offs[n] = carry;
}

// Bucket edges by destination: edata[offs[col]+k] = (row, dinv[row]*dinv[col])
__global__ __launch_bounds__(256) void k_fill(const int* __restrict__ ei,
                                              const int* __restrict__ offs,
                                              int* __restrict__ cursor,
                                              const float* __restrict__ dinv,
                                              int2* __restrict__ edata, int E) {
    int e = blockIdx.x * 256 + threadIdx.x;
    if (e >= E) return;
    int r = ei[e];
    int c = ei[E + e];
    int pos = atomicAdd(&cursor[c], 1);
    int2 d;
    d.x = r;
    d.y = __float_as_int(dinv[r] * dinv[c]);
    edata[offs[c] + pos] = d;
}

// C[m][n] = sum_k X[m][k] * W[n][k]; K fixed = 128, N in {64,128}.
// 64x64 tile, 256 threads, 4x4 microtile. K processed in two 64-halves.
// LDS layout [k][m^swz], swz = ((k>>2)&7)<<2:
//   - staging writes spread over all 32 banks at 2-way (free)
//   - frag reads remain 16B-aligned ds_read_b128 (broadcast / 2-way)
__global__ __launch_bounds__(256) void k_gemm(const float* __restrict__ X,
                                              const float* __restrict__ W,
                                              float* __restrict__ C,
                                              int M, int N) {
    __shared__ float Xs[64][64];  // 16 KB
    __shared__ float Ws[64][64];  // 16 KB
    const int tid = threadIdx.x;
    const int m0 = blockIdx.x * 64;
    const int n0 = blockIdx.y * 64;

    const int tx = tid & 15;   // n quad
    const int ty = tid >> 4;   // m quad
    float acc[4][4] = {};

    const int r = tid >> 2;          // staging row 0..63
    const int jb = tid & 3;          // float4 slot base; j = jb + 4*it

#pragma unroll
    for (int half = 0; half < 2; ++half) {
        const int k0q = half * 16;   // float4 index offset along K
        // ---- stage 64 rows x 64 k for X and W
#pragma unroll
        for (int it = 0; it < 4; ++it) {
            int j = jb + 4 * it;     // float4 index within the 64-k half
            int gm = m0 + r;
            float4 v = make_float4(0.f, 0.f, 0.f, 0.f);
            if (gm < M) v = reinterpret_cast<const float4*>(X + (size_t)gm * 128)[k0q + j];
            float4 w = reinterpret_cast<const float4*>(W + (size_t)(n0 + r) * 128)[k0q + j];
            int swz = (j & 7) << 2;          // ((k>>2)&7)<<2, k = 4j+d
            int col = r ^ swz;
            Xs[4 * j + 0][col] = v.x; Xs[4 * j + 1][col] = v.y;
            Xs[4 * j + 2][col] = v.z; Xs[4 * j + 3][col] = v.w;
            Ws[4 * j + 0][col] = w.x; Ws[4 * j + 1][col] = w.y;
            Ws[4 * j + 2][col] = w.z; Ws[4 * j + 3][col] = w.w;
        }
        __syncthreads();

        // ---- 64-k inner loop
#pragma unroll 4
        for (int k = 0; k < 64; ++k) {
            int swz = ((k >> 2) & 7) << 2;
            float4 a = *reinterpret_cast<const float4*>(&Xs[k][(4 * ty) ^ swz]);
            float4 b = *reinterpret_cast<const float4*>(&Ws[k][(4 * tx) ^ swz]);
            acc[0][0] += a.x * b.x; acc[0][1] += a.x * b.y; acc[0][2] += a.x * b.z; acc[0][3] += a.x * b.w;
            acc[1][0] += a.y * b.x; acc[1][1] += a.y * b.y; acc[1][2] += a.y * b.z; acc[1][3] += a.y * b.w;
            acc[2][0] += a.z * b.x; acc[2][1] += a.z * b.y; acc[2][2] += a.z * b.z; acc[2][3] += a.z * b.w;
            acc[3][0] += a.w * b.x; acc[3][1] += a.w * b.y; acc[3][2] += a.w * b.z; acc[3][3] += a.w * b.w;
        }
        if (half == 0) __syncthreads();
    }

#pragma unroll
    for (int rr = 0; rr < 4; ++rr) {
        int gm = m0 + 4 * ty + rr;
        if (gm < M) {
            float4 o = make_float4(acc[rr][0], acc[rr][1], acc[rr][2], acc[rr][3]);
            *reinterpret_cast<float4*>(C + (size_t)gm * N + n0 + 4 * tx) = o;
        }
    }
}

// H[dst][:] = relu?( dinv[dst]^2 * P[dst][:]
//                    + sum_{in-edges} norm * P[row][:] + bias )
template <int DQ, bool RELU>
__global__ __launch_bounds__(256) void k_gather(const float* __restrict__ P,
                                                const int* __restrict__ offs,
                                                const int2* __restrict__ edata,
                                                const float* __restrict__ dinv,
                                                const float* __restrict__ bias,
                                                float* __restrict__ H, int n) {
    int t = blockIdx.x * 256 + threadIdx.x;
    int node = t / DQ;
    int c = t % DQ;
    if (node >= n) return;
    const int D = DQ * 4;

    float s = dinv[node];
    s *= s;
    float4 pv = reinterpret_cast<const float4*>(P + (size_t)node * D)[c];
    float4 acc = make_float4(s * pv.x, s * pv.y, s * pv.z, s * pv.w);

    int j = offs[node];
    const int end = offs[node + 1];
    for (; j < end; ++j) {
        int2 ed = edata[j];
        float nrm = __int_as_float(ed.y);
        float4 v = reinterpret_cast<const float4*>(P + (size_t)ed.x * D)[c];
        acc.x += nrm * v.x; acc.y += nrm * v.y;
        acc.z += nrm * v.z; acc.w += nrm * v.w;
    }
    float4 b = reinterpret_cast<const float4*>(bias)[c];
    acc.x += b.x; acc.y += b.y; acc.z += b.z; acc.w += b.w;
    if (RELU) {
        acc.x = fmaxf(acc.x, 0.f); acc.y = fmaxf(acc.y, 0.f);
        acc.z = fmaxf(acc.z, 0.f); acc.w = fmaxf(acc.w, 0.f);
    }
    reinterpret_cast<float4*>(H + (size_t)node * D)[c] = acc;
}

extern "C" void kernel_launch(void* const* d_in, const int* in_sizes, int n_in,
                              void* d_out, int out_size, void* d_ws, size_t ws_size,
                              hipStream_t stream) {
    const float* x  = (const float*)d_in[0];
    const int*   ei = (const int*)d_in[1];   // [2][E] int32
    const float* W0 = (const float*)d_in[2];
    const float* b0 = (const float*)d_in[3];
    const float* W1 = (const float*)d_in[4];
    const float* b1 = (const float*)d_in[5];
    const float* W2 = (const float*)d_in[6];
    const float* b2 = (const float*)d_in[7];
    float* out = (float*)d_out;

    const int n = in_sizes[0] / 128;   // 50000
    const int E = in_sizes[1] / 2;     // 800000

    // workspace: counts | offs | cursor | dinv | edata | P | H   (~59 MB)
    int*   counts = (int*)d_ws;
    int*   offs   = counts + 51200;
    int*   cursor = offs + 51200;
    float* dinv   = (float*)(cursor + 51200);
    int2*  edata  = (int2*)(dinv + 51200);
    float* bufP   = (float*)(edata + E);
    float* bufH   = bufP + (size_t)n * 128;

    // ---- CSR build (once, reused by all 3 layers)
    hipMemsetAsync(counts, 0, (size_t)n * sizeof(int), stream);
    hipMemsetAsync(cursor, 0, (size_t)n * sizeof(int), stream);
    k_deg<<<(E + 255) / 256, 256, 0, stream>>>(ei, counts, E);
    k_dinv<<<(n + 255) / 256, 256, 0, stream>>>(counts, dinv, n);
    k_scan<<<1, 1024, 0, stream>>>(counts, offs, n);
    k_fill<<<(E + 255) / 256, 256, 0, stream>>>(ei, offs, cursor, dinv, edata, E);

    dim3 g128((n + 63) / 64, 2);
    dim3 g64((n + 63) / 64, 1);
    const int gThr128 = n * 32;  // DQ=32 lanes per node
    const int gThr64  = n * 16;  // DQ=16

    // ---- Layer 0: h = relu(propagate(x@W0^T) + b0)
    k_gemm<<<g128, 256, 0, stream>>>(x, W0, bufP, n, 128);
    k_gather<32, true><<<(gThr128 + 255) / 256, 256, 0, stream>>>(
        bufP, offs, edata, dinv, b0, bufH, n);

    // ---- Layer 1
    k_gemm<<<g128, 256, 0, stream>>>(bufH, W1, bufP, n, 128);
    k_gather<32, true><<<(gThr128 + 255) / 256, 256, 0, stream>>>(
        bufP, offs, edata, dinv, b1, bufH, n);

    // ---- Layer 2 (out dim 64, no relu)
    k_gemm<<<g64, 256, 0, stream>>>(bufH, W2, bufP, n, 64);
    k_gather<16, false><<<(gThr64 + 255) / 256, 256, 0, stream>>>(
        bufP, offs, edata, dinv, b2, out, n);
}

// Round 4
// 418.648 us; speedup vs baseline: 8.8522x; 1.0619x over previous
//
#include <hip/hip_runtime.h>

// ---------------------------------------------------------------------------
// PMLP forward: 3 x (GEMM -> symmetric-norm propagate -> bias[+relu])
// N=50000 nodes, E=800000 edges, dims 128->128->128->64, fp32.
// R2: scatter-atomics -> CSR-bucketed gather.
// R3: GEMM LDS XOR-swizzle + K-halving (conflicts -> 0, 5 blocks/CU).
// R4: gather 4-edge unroll, edata loads hoisted -> 4-way MLP on P loads.
// ---------------------------------------------------------------------------

__global__ __launch_bounds__(256) void k_deg(const int* __restrict__ ei,
                                             int* __restrict__ counts, int E) {
    int e = blockIdx.x * 256 + threadIdx.x;
    if (e < E) atomicAdd(&counts[ei[E + e]], 1);
}

__global__ __launch_bounds__(256) void k_dinv(const int* __restrict__ counts,
                                              float* __restrict__ dinv, int n) {
    int i = blockIdx.x * 256 + threadIdx.x;
    if (i < n) dinv[i] = rsqrtf((float)counts[i] + 1.0f);  // +1 = self loop
}

// Exclusive prefix sum of counts[0..n) -> offs[0..n]. Single block, 1024 thr.
__global__ __launch_bounds__(1024) void k_scan(const int* __restrict__ counts,
                                               int* __restrict__ offs, int n) {
    __shared__ int wsum[17];
    const int lane = threadIdx.x & 63;
    const int wid = threadIdx.x >> 6;  // 16 waves
    int carry = 0;
    for (int base = 0; base < n; base += 1024) {
        int i = base + threadIdx.x;
        int v = (i < n) ? counts[i] : 0;
        int s = v;
#pragma unroll
        for (int off = 1; off < 64; off <<= 1) {
            int t = __shfl_up(s, off);
            if (lane >= off) s += t;
        }
        if (lane == 63) wsum[wid] = s;
        __syncthreads();
        if (threadIdx.x == 0) {
            int a = 0;
            for (int w = 0; w < 16; ++w) { int t = wsum[w]; wsum[w] = a; a += t; }
            wsum[16] = a;
        }
        __syncthreads();
        if (i < n) offs[i] = carry + wsum[wid] + s - v;  // exclusive
        carry += wsum[16];
        __syncthreads();
    }
    if (threadIdx.x == 0) offs[n] = carry;
}

// Bucket edges by destination: edata[offs[col]+k] = (row, dinv[row]*dinv[col])
__global__ __launch_bounds__(256) void k_fill(const int* __restrict__ ei,
                                              const int* __restrict__ offs,
                                              int* __restrict__ cursor,
                                              const float* __restrict__ dinv,
                                              int2* __restrict__ edata, int E) {
    int e = blockIdx.x * 256 + threadIdx.x;
    if (e >= E) return;
    int r = ei[e];
    int c = ei[E + e];
    int pos = atomicAdd(&cursor[c], 1);
    int2 d;
    d.x = r;
    d.y = __float_as_int(dinv[r] * dinv[c]);
    edata[offs[c] + pos] = d;
}

// C[m][n] = sum_k X[m][k] * W[n][k]; K fixed = 128, N in {64,128}.
// 64x64 tile, 256 threads, 4x4 microtile. K processed in two 64-halves.
// LDS layout [k][m^swz], swz = ((k>>2)&7)<<2.
__global__ __launch_bounds__(256) void k_gemm(const float* __restrict__ X,
                                              const float* __restrict__ W,
                                              float* __restrict__ C,
                                              int M, int N) {
    __shared__ float Xs[64][64];  // 16 KB
    __shared__ float Ws[64][64];  // 16 KB
    const int tid = threadIdx.x;
    const int m0 = blockIdx.x * 64;
    const int n0 = blockIdx.y * 64;

    const int tx = tid & 15;   // n quad
    const int ty = tid >> 4;   // m quad
    float acc[4][4] = {};

    const int r = tid >> 2;          // staging row 0..63
    const int jb = tid & 3;          // float4 slot base; j = jb + 4*it

#pragma unroll
    for (int half = 0; half < 2; ++half) {
        const int k0q = half * 16;   // float4 index offset along K
#pragma unroll
        for (int it = 0; it < 4; ++it) {
            int j = jb + 4 * it;     // float4 index within the 64-k half
            int gm = m0 + r;
            float4 v = make_float4(0.f, 0.f, 0.f, 0.f);
            if (gm < M) v = reinterpret_cast<const float4*>(X + (size_t)gm * 128)[k0q + j];
            float4 w = reinterpret_cast<const float4*>(W + (size_t)(n0 + r) * 128)[k0q + j];
            int swz = (j & 7) << 2;          // ((k>>2)&7)<<2, k = 4j+d
            int col = r ^ swz;
            Xs[4 * j + 0][col] = v.x; Xs[4 * j + 1][col] = v.y;
            Xs[4 * j + 2][col] = v.z; Xs[4 * j + 3][col] = v.w;
            Ws[4 * j + 0][col] = w.x; Ws[4 * j + 1][col] = w.y;
            Ws[4 * j + 2][col] = w.z; Ws[4 * j + 3][col] = w.w;
        }
        __syncthreads();

#pragma unroll 4
        for (int k = 0; k < 64; ++k) {
            int swz = ((k >> 2) & 7) << 2;
            float4 a = *reinterpret_cast<const float4*>(&Xs[k][(4 * ty) ^ swz]);
            float4 b = *reinterpret_cast<const float4*>(&Ws[k][(4 * tx) ^ swz]);
            acc[0][0] += a.x * b.x; acc[0][1] += a.x * b.y; acc[0][2] += a.x * b.z; acc[0][3] += a.x * b.w;
            acc[1][0] += a.y * b.x; acc[1][1] += a.y * b.y; acc[1][2] += a.y * b.z; acc[1][3] += a.y * b.w;
            acc[2][0] += a.z * b.x; acc[2][1] += a.z * b.y; acc[2][2] += a.z * b.z; acc[2][3] += a.z * b.w;
            acc[3][0] += a.w * b.x; acc[3][1] += a.w * b.y; acc[3][2] += a.w * b.z; acc[3][3] += a.w * b.w;
        }
        if (half == 0) __syncthreads();
    }

#pragma unroll
    for (int rr = 0; rr < 4; ++rr) {
        int gm = m0 + 4 * ty + rr;
        if (gm < M) {
            float4 o = make_float4(acc[rr][0], acc[rr][1], acc[rr][2], acc[rr][3]);
            *reinterpret_cast<float4*>(C + (size_t)gm * N + n0 + 4 * tx) = o;
        }
    }
}

// H[dst][:] = relu?( dinv[dst]^2 * P[dst][:]
//                    + sum_{in-edges} norm * P[row][:] + bias )
// 4-edge unrolled: edata[j..j+3] loaded first, then 4 independent P loads
// in flight (memory-level parallelism on the latency-bound random gather).
template <int DQ, bool RELU>
__global__ __launch_bounds__(256) void k_gather(const float* __restrict__ P,
                                                const int* __restrict__ offs,
                                                const int2* __restrict__ edata,
                                                const float* __restrict__ dinv,
                                                const float* __restrict__ bias,
                                                float* __restrict__ H, int n) {
    int t = blockIdx.x * 256 + threadIdx.x;
    int node = t / DQ;
    int c = t % DQ;
    if (node >= n) return;
    const int D = DQ * 4;

    float s = dinv[node];
    s *= s;
    float4 pv = reinterpret_cast<const float4*>(P + (size_t)node * D)[c];
    float4 acc = make_float4(s * pv.x, s * pv.y, s * pv.z, s * pv.w);
    float4 acc2 = make_float4(0.f, 0.f, 0.f, 0.f);

    int j = offs[node];
    const int end = offs[node + 1];
    for (; j + 4 <= end; j += 4) {
        int2 e0 = edata[j + 0];
        int2 e1 = edata[j + 1];
        int2 e2 = edata[j + 2];
        int2 e3 = edata[j + 3];
        float4 v0 = reinterpret_cast<const float4*>(P + (size_t)e0.x * D)[c];
        float4 v1 = reinterpret_cast<const float4*>(P + (size_t)e1.x * D)[c];
        float4 v2 = reinterpret_cast<const float4*>(P + (size_t)e2.x * D)[c];
        float4 v3 = reinterpret_cast<const float4*>(P + (size_t)e3.x * D)[c];
        float n0 = __int_as_float(e0.y), n1 = __int_as_float(e1.y);
        float n2 = __int_as_float(e2.y), n3 = __int_as_float(e3.y);
        acc.x += n0 * v0.x; acc.y += n0 * v0.y; acc.z += n0 * v0.z; acc.w += n0 * v0.w;
        acc2.x += n1 * v1.x; acc2.y += n1 * v1.y; acc2.z += n1 * v1.z; acc2.w += n1 * v1.w;
        acc.x += n2 * v2.x; acc.y += n2 * v2.y; acc.z += n2 * v2.z; acc.w += n2 * v2.w;
        acc2.x += n3 * v3.x; acc2.y += n3 * v3.y; acc2.z += n3 * v3.z; acc2.w += n3 * v3.w;
    }
    for (; j < end; ++j) {
        int2 ed = edata[j];
        float nrm = __int_as_float(ed.y);
        float4 v = reinterpret_cast<const float4*>(P + (size_t)ed.x * D)[c];
        acc.x += nrm * v.x; acc.y += nrm * v.y;
        acc.z += nrm * v.z; acc.w += nrm * v.w;
    }
    float4 b = reinterpret_cast<const float4*>(bias)[c];
    acc.x += acc2.x + b.x; acc.y += acc2.y + b.y;
    acc.z += acc2.z + b.z; acc.w += acc2.w + b.w;
    if (RELU) {
        acc.x = fmaxf(acc.x, 0.f); acc.y = fmaxf(acc.y, 0.f);
        acc.z = fmaxf(acc.z, 0.f); acc.w = fmaxf(acc.w, 0.f);
    }
    reinterpret_cast<float4*>(H + (size_t)node * D)[c] = acc;
}

extern "C" void kernel_launch(void* const* d_in, const int* in_sizes, int n_in,
                              void* d_out, int out_size, void* d_ws, size_t ws_size,
                              hipStream_t stream) {
    const float* x  = (const float*)d_in[0];
    const int*   ei = (const int*)d_in[1];   // [2][E] int32
    const float* W0 = (const float*)d_in[2];
    const float* b0 = (const float*)d_in[3];
    const float* W1 = (const float*)d_in[4];
    const float* b1 = (const float*)d_in[5];
    const float* W2 = (const float*)d_in[6];
    const float* b2 = (const float*)d_in[7];
    float* out = (float*)d_out;

    const int n = in_sizes[0] / 128;   // 50000
    const int E = in_sizes[1] / 2;     // 800000

    // workspace: counts | offs | cursor | dinv | edata | P | H   (~59 MB)
    int*   counts = (int*)d_ws;
    int*   offs   = counts + 51200;
    int*   cursor = offs + 51200;
    float* dinv   = (float*)(cursor + 51200);
    int2*  edata  = (int2*)(dinv + 51200);
    float* bufP   = (float*)(edata + E);
    float* bufH   = bufP + (size_t)n * 128;

    // ---- CSR build (once, reused by all 3 layers)
    hipMemsetAsync(counts, 0, (size_t)n * sizeof(int), stream);
    hipMemsetAsync(cursor, 0, (size_t)n * sizeof(int), stream);
    k_deg<<<(E + 255) / 256, 256, 0, stream>>>(ei, counts, E);
    k_dinv<<<(n + 255) / 256, 256, 0, stream>>>(counts, dinv, n);
    k_scan<<<1, 1024, 0, stream>>>(counts, offs, n);
    k_fill<<<(E + 255) / 256, 256, 0, stream>>>(ei, offs, cursor, dinv, edata, E);

    dim3 g128((n + 63) / 64, 2);
    dim3 g64((n + 63) / 64, 1);
    const int gThr128 = n * 32;  // DQ=32 lanes per node
    const int gThr64  = n * 16;  // DQ=16

    // ---- Layer 0: h = relu(propagate(x@W0^T) + b0)
    k_gemm<<<g128, 256, 0, stream>>>(x, W0, bufP, n, 128);
    k_gather<32, true><<<(gThr128 + 255) / 256, 256, 0, stream>>>(
        bufP, offs, edata, dinv, b0, bufH, n);

    // ---- Layer 1
    k_gemm<<<g128, 256, 0, stream>>>(bufH, W1, bufP, n, 128);
    k_gather<32, true><<<(gThr128 + 255) / 256, 256, 0, stream>>>(
        bufP, offs, edata, dinv, b1, bufH, n);

    // ---- Layer 2 (out dim 64, no relu)
    k_gemm<<<g64, 256, 0, stream>>>(bufH, W2, bufP, n, 64);
    k_gather<16, false><<<(gThr64 + 255) / 256, 256, 0, stream>>>(
        bufP, offs, edata, dinv, b2, out, n);
}